// Round 3
// baseline (575.576 us; speedup 1.0000x reference)
//
#include <hip/hip_runtime.h>

#define NQ 1024
#define NO 2048
#define LAT 128
#define HD 32
#define CHUNK 32
#define NCHUNK (NO / CHUNK)          // 64
#define LOG2E 1.4426950408889634f
#define NEG_BIG -3.0e38f
#define PART_STRIDE 136   // 4 m + 4 lsum + 128 acc (floats per (slot,q))

// ---------------------------------------------------------------------------
// value path: h_obs <- LayerNorm(h_obs) @ Wv + bv (in place).
// 16 obs per block so Wv is streamed once per block (broadcast across the
// 16 obs-groups) instead of once per obs.
// ---------------------------------------------------------------------------
__global__ __launch_bounds__(256) void gano_value(
    const float* __restrict__ ln_g,
    const float* __restrict__ ln_b,
    const float* __restrict__ Wv,
    const float* __restrict__ bv,
    float* __restrict__ h)
{
    __shared__ __align__(16) float hn[16][LAT];   // 8 KB
    const int t = threadIdx.x;
    const int o = t >> 4;           // obs within block, 0..15
    const int i = t & 15;           // 16 threads per obs
    const int ob = blockIdx.x * 16 + o;
    float* hp = h + (size_t)ob * LAT + i * 8;

    // LN over the 8 dims this thread owns; reduce across the 16-lane group
    float4 a = *(const float4*)hp;
    float4 b = *(const float4*)(hp + 4);
    float s1 = a.x+a.y+a.z+a.w + b.x+b.y+b.z+b.w;
    float s2 = a.x*a.x+a.y*a.y+a.z*a.z+a.w*a.w
             + b.x*b.x+b.y*b.y+b.z*b.z+b.w*b.w;
#pragma unroll
    for (int off = 8; off >= 1; off >>= 1) {
        s1 += __shfl_xor(s1, off);
        s2 += __shfl_xor(s2, off);
    }
    const float mean = s1 * (1.0f/LAT);
    const float var  = s2 * (1.0f/LAT) - mean*mean;
    const float rstd = rsqrtf(var + 1e-5f);
    const int d0 = i * 8;
    const float4 g0 = *(const float4*)(ln_g + d0);
    const float4 g1 = *(const float4*)(ln_g + d0 + 4);
    const float4 e0 = *(const float4*)(ln_b + d0);
    const float4 e1 = *(const float4*)(ln_b + d0 + 4);
    float4 n0, n1;
    n0.x = (a.x-mean)*rstd*g0.x + e0.x;  n0.y = (a.y-mean)*rstd*g0.y + e0.y;
    n0.z = (a.z-mean)*rstd*g0.z + e0.z;  n0.w = (a.w-mean)*rstd*g0.w + e0.w;
    n1.x = (b.x-mean)*rstd*g1.x + e1.x;  n1.y = (b.y-mean)*rstd*g1.y + e1.y;
    n1.z = (b.z-mean)*rstd*g1.z + e1.z;  n1.w = (b.w-mean)*rstd*g1.w + e1.w;
    *(float4*)(&hn[o][d0])     = n0;
    *(float4*)(&hn[o][d0 + 4]) = n1;
    __syncthreads();

    // v[ob][d0..d0+8) = hn[o] @ Wv[:, d0..d0+8) + bv
    float4 c0 = *(const float4*)(bv + d0);
    float4 c1 = *(const float4*)(bv + d0 + 4);
#pragma unroll 4
    for (int kk = 0; kk < LAT; ++kk) {
        const float hk = hn[o][kk];                  // broadcast in 16-group
        const float4 w0 = *(const float4*)(Wv + kk*LAT + d0);
        const float4 w1 = *(const float4*)(Wv + kk*LAT + d0 + 4);
        c0.x = fmaf(hk, w0.x, c0.x);  c0.y = fmaf(hk, w0.y, c0.y);
        c0.z = fmaf(hk, w0.z, c0.z);  c0.w = fmaf(hk, w0.w, c0.w);
        c1.x = fmaf(hk, w1.x, c1.x);  c1.y = fmaf(hk, w1.y, c1.y);
        c1.z = fmaf(hk, w1.z, c1.z);  c1.w = fmaf(hk, w1.w, c1.w);
    }
    *(float4*)hp       = c0;   // safe: h[ob] fully consumed before barrier
    *(float4*)(hp + 4) = c1;
}

// ---------------------------------------------------------------------------
// main: 4 threads per query (thread k owns head k = dims [32k,32k+32)).
// preact = c_q[d] + d_o[d] + W1[9][d]*dist ; hidden = relu(preact)
// logits = hidden @ W2 (quad-shuffle reduce) ; online softmax (log2 domain)
// obs processed in PAIRS: amortizes the loop-invariant lw2 LDS reads and
// the alpha rescale (one exp2 for alpha per pair, not per obs).
// CHUNK=32 -> LDS 36.9 KB -> 4 blocks/CU (vs 2 at CHUNK=56).
// ---------------------------------------------------------------------------
__global__ __launch_bounds__(256, 4) void gano_main(
    const float* __restrict__ v,          // h_obs buffer, now holding v
    const float* __restrict__ pos_obs,
    const float* __restrict__ pos_query,
    const int* __restrict__ obs_batch,
    const int* __restrict__ query_batch,
    const float* __restrict__ W1,
    const float* __restrict__ b1,
    const float* __restrict__ W2,
    const float* __restrict__ b2,
    float* __restrict__ ws,
    float* __restrict__ out,
    int SY)
{
    __shared__ __align__(16) float ld[CHUNK*LAT];   // d_o tile     16 KB
    __shared__ __align__(16) float lv[CHUNK*LAT];   // v tile       16 KB
    __shared__ __align__(16) float lw2[LAT*4];      // W2*log2e      2 KB
    __shared__ __align__(16) float w1d[3*LAT];      // W1[3+a]-W1[6+a]
    __shared__ float lpos[CHUNK*3];
    __shared__ int   lob[CHUNK];

    const int tid = threadIdx.x;
    const int k  = tid & 3;       // head / dim-slot
    const int qi = tid >> 2;      // query within block
    const int q  = blockIdx.x * 64 + qi;

    // per-block LDS constants (visible after first in-loop barrier)
    lw2[tid]       = W2[tid]       * LOG2E;
    lw2[tid + 256] = W2[tid + 256] * LOG2E;
    for (int i = tid; i < 3*LAT; i += 256) {
        const int a = i >> 7, dd = i & 127;
        w1d[i] = W1[(3+a)*LAT + dd] - W1[(6+a)*LAT + dd];
    }

    const float pqx = pos_query[q*3+0];
    const float pqy = pos_query[q*3+1];
    const float pqz = pos_query[q*3+2];
    const int   qb  = query_batch[q];
    const float b2k = b2[k] * LOG2E;

    float4 cq[8], wd[8], acc[8];
#pragma unroll
    for (int j = 0; j < 8; ++j) {
        const int g4 = ((j + k) & 7) * 4;
        const int d0 = k*HD + g4;
        float4 c = *(const float4*)(b1 + d0);
        const float pq_[3] = {pqx, pqy, pqz};
#pragma unroll
        for (int a = 0; a < 3; ++a) {
            const float4 w0 = *(const float4*)(W1 + a*LAT + d0);
            const float4 w6 = *(const float4*)(W1 + (6+a)*LAT + d0);
            c.x = fmaf(pq_[a], w0.x + w6.x, c.x);
            c.y = fmaf(pq_[a], w0.y + w6.y, c.y);
            c.z = fmaf(pq_[a], w0.z + w6.z, c.z);
            c.w = fmaf(pq_[a], w0.w + w6.w, c.w);
        }
        cq[j] = c;
        wd[j] = *(const float4*)(W1 + 9*LAT + d0);
        acc[j] = make_float4(0.f, 0.f, 0.f, 0.f);
    }

    float m = NEG_BIG, lsum = 0.f;

    for (int cb = blockIdx.y; cb < NCHUNK; cb += SY) {
        const int o0 = cb * CHUNK;
        __syncthreads();   // previous chunk fully consumed / constants ready
        {
            for (int i = tid; i < CHUNK*(LAT/4); i += 256) {
                const int oo = i >> 5;          // obs within chunk
                const int d4 = (i & 31) * 4;    // dim group
                const float* po = pos_obs + (size_t)(o0 + oo)*3;
                const float px = po[0], py = po[1], pz = po[2];
                const float4 wa = *(const float4*)(w1d + 0*LAT + d4);
                const float4 wb = *(const float4*)(w1d + 1*LAT + d4);
                const float4 wc = *(const float4*)(w1d + 2*LAT + d4);
                float4 r;
                r.x = fmaf(px, wa.x, fmaf(py, wb.x, pz*wc.x));
                r.y = fmaf(px, wa.y, fmaf(py, wb.y, pz*wc.y));
                r.z = fmaf(px, wa.z, fmaf(py, wb.z, pz*wc.z));
                r.w = fmaf(px, wa.w, fmaf(py, wb.w, pz*wc.w));
                *(float4*)(ld + oo*LAT + d4) = r;
                *(float4*)(lv + oo*LAT + d4) =
                    *(const float4*)(v + (size_t)(o0+oo)*LAT + d4);
            }
            for (int i = tid; i < CHUNK*3; i += 256) lpos[i] = pos_obs[o0*3 + i];
            for (int i = tid; i < CHUNK;   i += 256) lob[i]  = obs_batch[o0 + i];
        }
        __syncthreads();

#pragma unroll 1
        for (int oc = 0; oc < CHUNK; oc += 2) {
            const float dx0 = pqx - lpos[oc*3+0];
            const float dy0 = pqy - lpos[oc*3+1];
            const float dz0 = pqz - lpos[oc*3+2];
            const float dx1 = pqx - lpos[oc*3+3];
            const float dy1 = pqy - lpos[oc*3+4];
            const float dz1 = pqz - lpos[oc*3+5];
            const float dist0 = sqrtf(dx0*dx0 + dy0*dy0 + dz0*dz0);
            const float dist1 = sqrtf(dx1*dx1 + dy1*dy1 + dz1*dz1);
            const int mb0 = (lob[oc]   == qb);
            const int mb1 = (lob[oc+1] == qb);

            float a0 = 0.f, a1 = 0.f, a2 = 0.f, a3 = 0.f;   // logits obs0
            float c0 = 0.f, c1 = 0.f, c2 = 0.f, c3 = 0.f;   // logits obs1
            const float* dbase = ld + oc*LAT + k*HD;
#pragma unroll
            for (int j = 0; j < 8; ++j) {
                const int g4 = ((j + k) & 7) * 4;
                const float4 dA = *(const float4*)(dbase + g4);
                const float4 dB = *(const float4*)(dbase + LAT + g4);
                const float4 base = make_float4(cq[j].x + dA.x, cq[j].y + dA.y,
                                                cq[j].z + dA.z, cq[j].w + dA.w);
                const float4 basB = make_float4(cq[j].x + dB.x, cq[j].y + dB.y,
                                                cq[j].z + dB.z, cq[j].w + dB.w);
                const float h0 = fmaxf(fmaf(wd[j].x, dist0, base.x), 0.f);
                const float h1 = fmaxf(fmaf(wd[j].y, dist0, base.y), 0.f);
                const float h2 = fmaxf(fmaf(wd[j].z, dist0, base.z), 0.f);
                const float h3 = fmaxf(fmaf(wd[j].w, dist0, base.w), 0.f);
                const float g0 = fmaxf(fmaf(wd[j].x, dist1, basB.x), 0.f);
                const float g1 = fmaxf(fmaf(wd[j].y, dist1, basB.y), 0.f);
                const float g2 = fmaxf(fmaf(wd[j].z, dist1, basB.z), 0.f);
                const float g3 = fmaxf(fmaf(wd[j].w, dist1, basB.w), 0.f);
                const int l4 = (k*HD + g4) * 4;
                const float4 wa = *(const float4*)(lw2 + l4);
                const float4 wb = *(const float4*)(lw2 + l4 + 4);
                const float4 wc = *(const float4*)(lw2 + l4 + 8);
                const float4 we = *(const float4*)(lw2 + l4 + 12);
                a0 = fmaf(h0, wa.x, a0); a1 = fmaf(h0, wa.y, a1);
                a2 = fmaf(h0, wa.z, a2); a3 = fmaf(h0, wa.w, a3);
                c0 = fmaf(g0, wa.x, c0); c1 = fmaf(g0, wa.y, c1);
                c2 = fmaf(g0, wa.z, c2); c3 = fmaf(g0, wa.w, c3);
                a0 = fmaf(h1, wb.x, a0); a1 = fmaf(h1, wb.y, a1);
                a2 = fmaf(h1, wb.z, a2); a3 = fmaf(h1, wb.w, a3);
                c0 = fmaf(g1, wb.x, c0); c1 = fmaf(g1, wb.y, c1);
                c2 = fmaf(g1, wb.z, c2); c3 = fmaf(g1, wb.w, c3);
                a0 = fmaf(h2, wc.x, a0); a1 = fmaf(h2, wc.y, a1);
                a2 = fmaf(h2, wc.z, a2); a3 = fmaf(h2, wc.w, a3);
                c0 = fmaf(g2, wc.x, c0); c1 = fmaf(g2, wc.y, c1);
                c2 = fmaf(g2, wc.z, c2); c3 = fmaf(g2, wc.w, c3);
                a0 = fmaf(h3, we.x, a0); a1 = fmaf(h3, we.y, a1);
                a2 = fmaf(h3, we.z, a2); a3 = fmaf(h3, we.w, a3);
                c0 = fmaf(g3, we.x, c0); c1 = fmaf(g3, we.y, c1);
                c2 = fmaf(g3, we.z, c2); c3 = fmaf(g3, we.w, c3);
            }
            // quad-reduce the 4 partial sums (lanes k=0..3 of this query)
            a0 += __shfl_xor(a0, 1); a0 += __shfl_xor(a0, 2);
            a1 += __shfl_xor(a1, 1); a1 += __shfl_xor(a1, 2);
            a2 += __shfl_xor(a2, 1); a2 += __shfl_xor(a2, 2);
            a3 += __shfl_xor(a3, 1); a3 += __shfl_xor(a3, 2);
            c0 += __shfl_xor(c0, 1); c0 += __shfl_xor(c0, 2);
            c1 += __shfl_xor(c1, 1); c1 += __shfl_xor(c1, 2);
            c2 += __shfl_xor(c2, 1); c2 += __shfl_xor(c2, 2);
            c3 += __shfl_xor(c3, 1); c3 += __shfl_xor(c3, 2);
            float l0 = (k == 0) ? a0 : ((k == 1) ? a1 : ((k == 2) ? a2 : a3));
            float l1 = (k == 0) ? c0 : ((k == 1) ? c1 : ((k == 2) ? c2 : c3));
            l0 += b2k;  l1 += b2k;
            l0 = mb0 ? l0 : NEG_BIG;
            l1 = mb1 ? l1 : NEG_BIG;

            const float mn    = fmaxf(m, fmaxf(l0, l1));
            const float alpha = exp2f(m - mn);
            const float p0    = mb0 ? exp2f(l0 - mn) : 0.f;
            const float p1    = mb1 ? exp2f(l1 - mn) : 0.f;
            lsum = fmaf(lsum, alpha, p0 + p1);
            m = mn;

            const float* vbase = lv + oc*LAT + k*HD;
#pragma unroll
            for (int j = 0; j < 8; ++j) {
                const int g4 = ((j + k) & 7) * 4;
                const float4 v0 = *(const float4*)(vbase + g4);
                const float4 v1 = *(const float4*)(vbase + LAT + g4);
                acc[j].x = fmaf(acc[j].x, alpha, fmaf(p0, v0.x, p1*v1.x));
                acc[j].y = fmaf(acc[j].y, alpha, fmaf(p0, v0.y, p1*v1.y));
                acc[j].z = fmaf(acc[j].z, alpha, fmaf(p0, v0.z, p1*v1.z));
                acc[j].w = fmaf(acc[j].w, alpha, fmaf(p0, v0.w, p1*v1.w));
            }
        }
    }

    if (SY == 1) {
        const float inv = 1.0f / lsum;
        float* op = out + (size_t)q*LAT + k*HD;
#pragma unroll
        for (int j = 0; j < 8; ++j) {
            const int g4 = ((j + k) & 7) * 4;
            float4 r;
            r.x = acc[j].x * inv; r.y = acc[j].y * inv;
            r.z = acc[j].z * inv; r.w = acc[j].w * inv;
            *(float4*)(op + g4) = r;
        }
    } else {
        float* pp = ws + ((size_t)blockIdx.y * NQ + q) * PART_STRIDE;
        pp[k] = m;
        pp[4 + k] = lsum;
#pragma unroll
        for (int j = 0; j < 8; ++j) {
            const int g4 = ((j + k) & 7) * 4;
            *(float4*)(pp + 8 + k*HD + g4) = acc[j];
        }
    }
}

// ---------------------------------------------------------------------------
// combine: merge SY partials per query (log2-domain online merge), normalize
// ---------------------------------------------------------------------------
__global__ __launch_bounds__(128) void gano_combine(
    const float* __restrict__ ws, float* __restrict__ out, int SY)
{
    const int q = blockIdx.x;
    const int l = threadIdx.x;
    const int h = l >> 5;
    float M = NEG_BIG, Ls = 0.f, A = 0.f;
    for (int s = 0; s < SY; ++s) {
        const float* pp = ws + ((size_t)s * NQ + q) * PART_STRIDE;
        const float ms = pp[h];
        const float ls = pp[4 + h];
        const float as = pp[8 + l];
        const float Mn = fmaxf(M, ms);
        const float a0 = exp2f(M - Mn);
        const float a1 = exp2f(ms - Mn);
        Ls = Ls*a0 + ls*a1;
        A  = A *a0 + as*a1;
        M = Mn;
    }
    out[(size_t)q*LAT + l] = A / Ls;
}

// ---------------------------------------------------------------------------
extern "C" void kernel_launch(void* const* d_in, const int* in_sizes, int n_in,
                              void* d_out, int out_size, void* d_ws, size_t ws_size,
                              hipStream_t stream) {
    (void)in_sizes; (void)n_in; (void)out_size;
    float*       h_obs     = (float*)d_in[0];        // mutated in place -> v
    const float* pos_obs   = (const float*)d_in[1];
    const float* pos_query = (const float*)d_in[2];
    const int*   obs_batch = (const int*)d_in[3];
    const int*   query_batch = (const int*)d_in[4];
    const float* W1 = (const float*)d_in[5];
    const float* b1 = (const float*)d_in[6];
    const float* W2 = (const float*)d_in[7];
    const float* b2 = (const float*)d_in[8];
    const float* ln_g = (const float*)d_in[9];
    const float* ln_b = (const float*)d_in[10];
    const float* Wv = (const float*)d_in[11];
    const float* bv = (const float*)d_in[12];
    float* ws  = (float*)d_ws;
    float* out = (float*)d_out;

    // split-O factor, strictly bounded by what d_ws can hold (0 bytes @ SY=1)
    int SY = 1;
    const size_t per = (size_t)NQ * PART_STRIDE * sizeof(float);
    if (ws && ws_size >= 2*per) {
        size_t s = ws_size / per;
        SY = (int)(s < NCHUNK ? s : NCHUNK);
    }

    gano_value<<<NO/16, 256, 0, stream>>>(ln_g, ln_b, Wv, bv, h_obs);
    gano_main<<<dim3(NQ/64, SY), 256, 0, stream>>>(h_obs, pos_obs, pos_query,
                                                   obs_batch, query_batch,
                                                   W1, b1, W2, b2, ws, out, SY);
    if (SY > 1)
        gano_combine<<<NQ, 128, 0, stream>>>(ws, out, SY);
}

// Round 4
// 214.390 us; speedup vs baseline: 2.6847x; 2.6847x over previous
//
#include <hip/hip_runtime.h>

#define NQ 1024
#define NO 2048
#define LAT 128
#define CHUNK 32
#define NCHUNK (NO / CHUNK)          // 64
#define LOG2E 1.4426950408889634f
#define NEG_BIG -3.0e38f
#define PART_STRIDE 136   // 4 m + 4 lsum + 128 acc (floats per (slot,q))

// ---------------------------------------------------------------------------
// value path: h_obs <- LayerNorm(h_obs) @ Wv + bv (in place).
// 8 obs per block, 32 threads per obs (4 dims each): 256 blocks -> 1/CU,
// serial k-chain halved vs the 8-dim/thread version.
// ---------------------------------------------------------------------------
__global__ __launch_bounds__(256) void gano_value(
    const float* __restrict__ ln_g,
    const float* __restrict__ ln_b,
    const float* __restrict__ Wv,
    const float* __restrict__ bv,
    float* __restrict__ h)
{
    __shared__ __align__(16) float hn[8][LAT];   // 4 KB
    const int t = threadIdx.x;
    const int o = t >> 5;           // obs within block, 0..7
    const int i = t & 31;           // 32 threads per obs
    const int ob = blockIdx.x * 8 + o;
    const int d0 = i * 4;
    float* hp = h + (size_t)ob * LAT + d0;

    float4 x = *(const float4*)hp;
    float s1 = x.x + x.y + x.z + x.w;
    float s2 = x.x*x.x + x.y*x.y + x.z*x.z + x.w*x.w;
#pragma unroll
    for (int off = 16; off >= 1; off >>= 1) {
        s1 += __shfl_xor(s1, off);
        s2 += __shfl_xor(s2, off);
    }
    const float mean = s1 * (1.0f/LAT);
    const float var  = s2 * (1.0f/LAT) - mean*mean;
    const float rstd = rsqrtf(var + 1e-5f);
    const float4 g = *(const float4*)(ln_g + d0);
    const float4 e = *(const float4*)(ln_b + d0);
    float4 n;
    n.x = (x.x-mean)*rstd*g.x + e.x;  n.y = (x.y-mean)*rstd*g.y + e.y;
    n.z = (x.z-mean)*rstd*g.z + e.z;  n.w = (x.w-mean)*rstd*g.w + e.w;
    *(float4*)(&hn[o][d0]) = n;
    __syncthreads();

    float4 c = *(const float4*)(bv + d0);
#pragma unroll 4
    for (int kk = 0; kk < LAT; ++kk) {
        const float hk = hn[o][kk];                  // broadcast in 32-group
        const float4 w = *(const float4*)(Wv + kk*LAT + d0);
        c.x = fmaf(hk, w.x, c.x);  c.y = fmaf(hk, w.y, c.y);
        c.z = fmaf(hk, w.z, c.z);  c.w = fmaf(hk, w.w, c.w);
    }
    *(float4*)hp = c;   // row ob fully consumed before the barrier
}

// ---------------------------------------------------------------------------
// main: 16 threads per query; thread i owns dims [i*8, i*8+8) (= head i>>2).
// W2 lives in REGISTERS (8 dims x 4 heads = 32 VGPR) -> no per-pair W2 LDS
// traffic (was 2 KB/pair, 2/3 of all LDS bytes in the R2 structure).
// preact = c_q[d] + d_o[d] + W1[9][d]*dist ; hidden = relu(preact)
// logit partials (4 heads) -> select-butterfly reduce over the 16-lane group.
// Online softmax in log2 domain; thread tracks m/lsum of its own head only.
// LDS float4-group swizzle slot = g ^ (g>>3): stride-8-float reads become
// 2-way (free) instead of 4-way bank conflicts.
// ---------------------------------------------------------------------------
__global__ __launch_bounds__(256, 2) void gano_main(
    const float* __restrict__ v,          // h_obs buffer, now holding v
    const float* __restrict__ pos_obs,
    const float* __restrict__ pos_query,
    const int* __restrict__ obs_batch,
    const int* __restrict__ query_batch,
    const float* __restrict__ W1,
    const float* __restrict__ b1,
    const float* __restrict__ W2,
    const float* __restrict__ b2,
    float* __restrict__ ws,
    float* __restrict__ out,
    int SY)
{
    __shared__ __align__(16) float ld[CHUNK*LAT];   // d_o tile (swizzled) 16 KB
    __shared__ __align__(16) float lv[CHUNK*LAT];   // v tile   (swizzled) 16 KB
    __shared__ __align__(16) float w1d[3*LAT];      // W1[3+a]-W1[6+a]   1.5 KB
    __shared__ float lpos[CHUNK*3];
    __shared__ int   lob[CHUNK];

    const int tid = threadIdx.x;
    const int i  = tid & 15;        // dim-slice owner within query
    const int qi = tid >> 4;        // query within block (0..15)
    const int q  = blockIdx.x * 16 + qi;
    const int d0 = i * 8;
    const int hstar = i >> 2;       // the head this thread's dims belong to

    // swizzled float offsets of this thread's two float4 groups
    const int g0 = 2*i,     s0 = (g0 ^ (g0 >> 3)) * 4;
    const int g1 = 2*i + 1, s1 = (g1 ^ (g1 >> 3)) * 4;

    // per-block LDS constant (covered by first in-loop barrier)
    for (int idx = tid; idx < 3*LAT; idx += 256) {
        const int a = idx >> 7, dd = idx & 127;
        w1d[idx] = W1[(3+a)*LAT + dd] - W1[(6+a)*LAT + dd];
    }

    const float pqx = pos_query[q*3+0];
    const float pqy = pos_query[q*3+1];
    const float pqz = pos_query[q*3+2];
    const int   qb  = query_batch[q];
    const float b2k = b2[hstar] * LOG2E;

    // registers: W2 rows for my 8 dims (pre-scaled by log2e), c_q, w_dist
    float w2f[8][4], cqf[8], wdf[8];
    {
        const float pq_[3] = {pqx, pqy, pqz};
        float4 c0 = *(const float4*)(b1 + d0);
        float4 c1 = *(const float4*)(b1 + d0 + 4);
#pragma unroll
        for (int a = 0; a < 3; ++a) {
            const float4 w0a = *(const float4*)(W1 + a*LAT + d0);
            const float4 w0b = *(const float4*)(W1 + a*LAT + d0 + 4);
            const float4 w6a = *(const float4*)(W1 + (6+a)*LAT + d0);
            const float4 w6b = *(const float4*)(W1 + (6+a)*LAT + d0 + 4);
            c0.x = fmaf(pq_[a], w0a.x + w6a.x, c0.x);
            c0.y = fmaf(pq_[a], w0a.y + w6a.y, c0.y);
            c0.z = fmaf(pq_[a], w0a.z + w6a.z, c0.z);
            c0.w = fmaf(pq_[a], w0a.w + w6a.w, c0.w);
            c1.x = fmaf(pq_[a], w0b.x + w6b.x, c1.x);
            c1.y = fmaf(pq_[a], w0b.y + w6b.y, c1.y);
            c1.z = fmaf(pq_[a], w0b.z + w6b.z, c1.z);
            c1.w = fmaf(pq_[a], w0b.w + w6b.w, c1.w);
        }
        cqf[0]=c0.x; cqf[1]=c0.y; cqf[2]=c0.z; cqf[3]=c0.w;
        cqf[4]=c1.x; cqf[5]=c1.y; cqf[6]=c1.z; cqf[7]=c1.w;
        const float4 wda = *(const float4*)(W1 + 9*LAT + d0);
        const float4 wdb = *(const float4*)(W1 + 9*LAT + d0 + 4);
        wdf[0]=wda.x; wdf[1]=wda.y; wdf[2]=wda.z; wdf[3]=wda.w;
        wdf[4]=wdb.x; wdf[5]=wdb.y; wdf[6]=wdb.z; wdf[7]=wdb.w;
#pragma unroll
        for (int j = 0; j < 8; ++j) {
            const float4 w = *(const float4*)(W2 + (d0 + j)*4);
            w2f[j][0] = w.x * LOG2E;  w2f[j][1] = w.y * LOG2E;
            w2f[j][2] = w.z * LOG2E;  w2f[j][3] = w.w * LOG2E;
        }
    }

    float4 accA = make_float4(0.f,0.f,0.f,0.f);
    float4 accB = make_float4(0.f,0.f,0.f,0.f);
    float m = NEG_BIG, lsum = 0.f;

    for (int cb = blockIdx.y; cb < NCHUNK; cb += SY) {
        const int o0 = cb * CHUNK;
        __syncthreads();   // previous chunk consumed / w1d ready
        for (int idx = tid; idx < CHUNK*32; idx += 256) {
            const int oo = idx >> 5;           // obs within chunk
            const int g  = idx & 31;           // float4 group
            const int d4 = g * 4;
            const int sg = (g ^ (g >> 3)) * 4; // swizzled slot
            const float* po = pos_obs + (size_t)(o0 + oo)*3;
            const float px = po[0], py = po[1], pz = po[2];
            const float4 wa = *(const float4*)(w1d + 0*LAT + d4);
            const float4 wb = *(const float4*)(w1d + 1*LAT + d4);
            const float4 wc = *(const float4*)(w1d + 2*LAT + d4);
            float4 r;
            r.x = fmaf(px, wa.x, fmaf(py, wb.x, pz*wc.x));
            r.y = fmaf(px, wa.y, fmaf(py, wb.y, pz*wc.y));
            r.z = fmaf(px, wa.z, fmaf(py, wb.z, pz*wc.z));
            r.w = fmaf(px, wa.w, fmaf(py, wb.w, pz*wc.w));
            *(float4*)(ld + oo*LAT + sg) = r;
            *(float4*)(lv + oo*LAT + sg) =
                *(const float4*)(v + (size_t)(o0+oo)*LAT + d4);
        }
        for (int idx = tid; idx < CHUNK*3; idx += 256) lpos[idx] = pos_obs[o0*3 + idx];
        for (int idx = tid; idx < CHUNK;   idx += 256) lob[idx]  = obs_batch[o0 + idx];
        __syncthreads();

#pragma unroll 1
        for (int oc = 0; oc < CHUNK; ++oc) {
            const float dx = pqx - lpos[oc*3+0];
            const float dy = pqy - lpos[oc*3+1];
            const float dz = pqz - lpos[oc*3+2];
            const float dist = sqrtf(dx*dx + dy*dy + dz*dz);
            const int mb = (lob[oc] == qb);

            const float* dptr = ld + oc*LAT;
            const float4 dA = *(const float4*)(dptr + s0);
            const float4 dB = *(const float4*)(dptr + s1);
            const float dval[8] = {dA.x, dA.y, dA.z, dA.w,
                                   dB.x, dB.y, dB.z, dB.w};
            float lg0 = 0.f, lg1 = 0.f, lg2 = 0.f, lg3 = 0.f;
#pragma unroll
            for (int j = 0; j < 8; ++j) {
                const float hj = fmaxf(fmaf(wdf[j], dist, cqf[j] + dval[j]), 0.f);
                lg0 = fmaf(hj, w2f[j][0], lg0);
                lg1 = fmaf(hj, w2f[j][1], lg1);
                lg2 = fmaf(hj, w2f[j][2], lg2);
                lg3 = fmaf(hj, w2f[j][3], lg3);
            }
            // reduce over the 16-lane group: fold to 4-lane classes, select
            // own head's partial, finish within the 4-lane subgroup
            lg0 += __shfl_xor(lg0, 8); lg0 += __shfl_xor(lg0, 4);
            lg1 += __shfl_xor(lg1, 8); lg1 += __shfl_xor(lg1, 4);
            lg2 += __shfl_xor(lg2, 8); lg2 += __shfl_xor(lg2, 4);
            lg3 += __shfl_xor(lg3, 8); lg3 += __shfl_xor(lg3, 4);
            float sel = (i & 8) ? ((i & 4) ? lg3 : lg2)
                                : ((i & 4) ? lg1 : lg0);
            sel += __shfl_xor(sel, 1);
            sel += __shfl_xor(sel, 2);

            float logit = sel + b2k;
            logit = mb ? logit : NEG_BIG;

            const float mn    = fmaxf(m, logit);
            const float alpha = exp2f(m - mn);
            const float p     = mb ? exp2f(logit - mn) : 0.f;
            lsum = fmaf(lsum, alpha, p);
            m = mn;

            const float* vptr = lv + oc*LAT;
            const float4 vA = *(const float4*)(vptr + s0);
            const float4 vB = *(const float4*)(vptr + s1);
            accA.x = fmaf(accA.x, alpha, p*vA.x);
            accA.y = fmaf(accA.y, alpha, p*vA.y);
            accA.z = fmaf(accA.z, alpha, p*vA.z);
            accA.w = fmaf(accA.w, alpha, p*vA.w);
            accB.x = fmaf(accB.x, alpha, p*vB.x);
            accB.y = fmaf(accB.y, alpha, p*vB.y);
            accB.z = fmaf(accB.z, alpha, p*vB.z);
            accB.w = fmaf(accB.w, alpha, p*vB.w);
        }
    }

    if (SY == 1) {
        const float inv = 1.0f / lsum;
        float* op = out + (size_t)q*LAT + d0;
        float4 rA, rB;
        rA.x = accA.x*inv; rA.y = accA.y*inv; rA.z = accA.z*inv; rA.w = accA.w*inv;
        rB.x = accB.x*inv; rB.y = accB.y*inv; rB.z = accB.z*inv; rB.w = accB.w*inv;
        *(float4*)op       = rA;
        *(float4*)(op + 4) = rB;
    } else {
        float* pp = ws + ((size_t)blockIdx.y * NQ + q) * PART_STRIDE;
        if ((i & 3) == 0) {          // one writer per head
            pp[hstar]     = m;
            pp[4 + hstar] = lsum;
        }
        *(float4*)(pp + 8 + d0)     = accA;   // dims stored unswizzled
        *(float4*)(pp + 8 + d0 + 4) = accB;
    }
}

// ---------------------------------------------------------------------------
// combine: merge SY partials per query (log2-domain online merge), normalize
// ---------------------------------------------------------------------------
__global__ __launch_bounds__(128) void gano_combine(
    const float* __restrict__ ws, float* __restrict__ out, int SY)
{
    const int q = blockIdx.x;
    const int l = threadIdx.x;
    const int h = l >> 5;
    float M = NEG_BIG, Ls = 0.f, A = 0.f;
    for (int s = 0; s < SY; ++s) {
        const float* pp = ws + ((size_t)s * NQ + q) * PART_STRIDE;
        const float ms = pp[h];
        const float ls = pp[4 + h];
        const float as = pp[8 + l];
        const float Mn = fmaxf(M, ms);
        const float a0 = exp2f(M - Mn);
        const float a1 = exp2f(ms - Mn);
        Ls = Ls*a0 + ls*a1;
        A  = A *a0 + as*a1;
        M = Mn;
    }
    out[(size_t)q*LAT + l] = A / Ls;
}

// ---------------------------------------------------------------------------
extern "C" void kernel_launch(void* const* d_in, const int* in_sizes, int n_in,
                              void* d_out, int out_size, void* d_ws, size_t ws_size,
                              hipStream_t stream) {
    (void)in_sizes; (void)n_in; (void)out_size;
    float*       h_obs     = (float*)d_in[0];        // mutated in place -> v
    const float* pos_obs   = (const float*)d_in[1];
    const float* pos_query = (const float*)d_in[2];
    const int*   obs_batch = (const int*)d_in[3];
    const int*   query_batch = (const int*)d_in[4];
    const float* W1 = (const float*)d_in[5];
    const float* b1 = (const float*)d_in[6];
    const float* W2 = (const float*)d_in[7];
    const float* b2 = (const float*)d_in[8];
    const float* ln_g = (const float*)d_in[9];
    const float* ln_b = (const float*)d_in[10];
    const float* Wv = (const float*)d_in[11];
    const float* bv = (const float*)d_in[12];
    float* ws  = (float*)d_ws;
    float* out = (float*)d_out;

    // split-O factor: 16 -> grid 64x16 = 1024 blocks = 4/CU exactly.
    // Strictly bounded by what d_ws can hold (0 bytes touched @ SY=1).
    int SY = 1;
    const size_t per = (size_t)NQ * PART_STRIDE * sizeof(float);
    if (ws && ws_size >= 2*per) {
        size_t s = ws_size / per;
        SY = (int)(s < 16 ? s : 16);
    }

    gano_value<<<NO/8, 256, 0, stream>>>(ln_g, ln_b, Wv, bv, h_obs);
    gano_main<<<dim3(NQ/16, SY), 256, 0, stream>>>(h_obs, pos_obs, pos_query,
                                                   obs_batch, query_batch,
                                                   W1, b1, W2, b2, ws, out, SY);
    if (SY > 1)
        gano_combine<<<NQ, 128, 0, stream>>>(ws, out, SY);
}